// Round 12
// baseline (396.501 us; speedup 1.0000x reference)
//
#include <hip/hip_runtime.h>
#include <hip/hip_bf16.h>

typedef __bf16 bf16;
typedef __bf16 bf16x8 __attribute__((ext_vector_type(8)));
typedef __bf16 bf16x4 __attribute__((ext_vector_type(4)));
typedef _Float16 f16;
typedef _Float16 f16x4 __attribute__((ext_vector_type(4)));
typedef _Float16 f16x8 __attribute__((ext_vector_type(8)));
typedef float f32x4 __attribute__((ext_vector_type(4)));

#define MFMA16(a, b, c)    __builtin_amdgcn_mfma_f32_16x16x32_bf16(a, b, c, 0, 0, 0)
#define MFMA16F16(a, b, c) __builtin_amdgcn_mfma_f32_16x16x16f16(a, b, c, 0, 0, 0)

// async global->LDS, 16B/lane; LDS dest = wave-uniform base + lane*16.
__device__ __forceinline__ void gll(const void* g, void* l) {
    __builtin_amdgcn_global_load_lds(
        (const __attribute__((address_space(1))) unsigned int*)g,
        (__attribute__((address_space(3))) unsigned int*)l, 16, 0, 0);
}

// ---------------- fused fp32 -> bf16 conversion (one launch) ----------------
__global__ void cvt_all(const float* __restrict__ x, const float* __restrict__ wq,
                        const float* __restrict__ wp, bf16* __restrict__ xb,
                        bf16* __restrict__ wqb, bf16* __restrict__ wpb) {
    int i = blockIdx.x * 256 + threadIdx.x;
    const float4* s; bf16* d; int j;
    if (i < 1048576)                { s = (const float4*)x;  d = xb;  j = i; }
    else if (i < 1048576 + 786432)  { s = (const float4*)wq; d = wqb; j = i - 1048576; }
    else                            { s = (const float4*)wp; d = wpb; j = i - 1835008; }
    float4 f = s[j];
    bf16x4 o; o[0] = (bf16)f.x; o[1] = (bf16)f.y; o[2] = (bf16)f.z; o[3] = (bf16)f.w;
    ((bf16x4*)d)[j] = o;
}

// Q pre-scale: head_dim^-0.5 * log2(e) -> softmax in exp2 domain
#define QSCALE 0.18033688f

// ================= Packed fragment layouts (per (b,h), per 64-token tile) =====
// Q/K (bf16): [tile32][frag8 = nb*2+ks][512 elems]; elem l*8+e of frag =
//   M[nb*16 + (l&15)][ks*32 + (l>>4)*8 + e]  -> attn loads b128 at lane*16B.
// V  (f16):  [tile32][kh2][jd4][512 elems]; elem l*8 + n*4 + c =
//   V^T[jd*16 + (l&15)][kh*32 + n*16 + (l>>4)*4 + c] -> b128 gives n=0/1 halves.

// ---------------- GEMM1: 128x128, dbuf gll; packed-fragment epilogues ---------
__global__ __launch_bounds__(256, 3) void gemm_qkv(
    const bf16* __restrict__ A, const bf16* __restrict__ Bm,
    bf16* __restrict__ qo, bf16* __restrict__ ko, f16* __restrict__ vo)
{
    __shared__ bf16 As[2][128 * 32];
    __shared__ bf16 Bs[2][128 * 32];
    const int tid = threadIdx.x;
    const int wave = tid >> 6, lane = tid & 63;
    const int lrow = lane & 15, quad = lane >> 4;
    const int wm = (wave >> 1) * 64, wn = (wave & 1) * 64;
    const int srow = tid >> 2;
    const int scol = ((tid & 3) ^ (srow & 3)) * 8;
    const int fsw = (quad ^ (lrow & 3)) * 8;

    const bf16* Ap = A + (long)(blockIdx.x * 128 + srow) * 1024 + scol;
    const bf16* Bp = Bm + (long)(blockIdx.y * 128 + srow) * 1024 + scol;

    f32x4 acc[4][4] = {};
    const int gm0 = blockIdx.x * 128 + wm;
    const int go0 = blockIdx.y * 128 + wn;

    gll(Ap, &As[0][tid * 8]);  gll(Ap + 64 * 1024, &As[0][2048 + tid * 8]);
    gll(Bp, &Bs[0][tid * 8]);  gll(Bp + 64 * 1024, &Bs[0][2048 + tid * 8]);

    if (blockIdx.y < 16) {   // ---- Q/K: transposed product (acc reg-index along d) ----
        for (int i = 0; i < 32; i++) {
            const int cur = i & 1;
            __syncthreads();
            if (i < 31) {
                const int k0 = (i + 1) * 32;
                gll(Ap + k0, &As[cur ^ 1][tid * 8]);
                gll(Ap + 64 * 1024 + k0, &As[cur ^ 1][2048 + tid * 8]);
                gll(Bp + k0, &Bs[cur ^ 1][tid * 8]);
                gll(Bp + 64 * 1024 + k0, &Bs[cur ^ 1][2048 + tid * 8]);
            }
            bf16x8 af[4], bfr[4];
#pragma unroll
            for (int ii = 0; ii < 4; ii++) af[ii] = *(const bf16x8*)&As[cur][(wm + ii * 16 + lrow) * 32 + fsw];
#pragma unroll
            for (int j = 0; j < 4; j++) bfr[j] = *(const bf16x8*)&Bs[cur][(wn + j * 16 + lrow) * 32 + fsw];
#pragma unroll
            for (int ii = 0; ii < 4; ii++)
#pragma unroll
                for (int j = 0; j < 4; j++)
                    acc[ii][j] = MFMA16(bfr[j], af[ii], acc[ii][j]);
        }
        // ---- packed store: token range = one tile (64 rows) per wave ----
        const bool isQ = blockIdx.y < 8;
        bf16* dst = isQ ? qo : ko;
        const float sc = isQ ? QSCALE : 1.0f;
        const int b = gm0 >> 11;
        const int h = (go0 & 1023) >> 6;                 // one head per wave (wn=64-aligned)
        const long tbase = ((long)(b * 16 + h) * 32 + ((gm0 >> 6) & 31)) * 4096;
#pragma unroll
        for (int i = 0; i < 4; i++)                      // i = nb (token n-block)
#pragma unroll
            for (int j = 0; j < 4; j++) {                // d = j*16 + quad*4 + r
                bf16x4 pk;
#pragma unroll
                for (int r = 0; r < 4; r++) pk[r] = (bf16)(acc[i][j][r] * sc);
                long Aoff = tbase + (i * 2 + (j >> 1)) * 512
                          + ((j & 1) * 2 + (quad >> 1)) * 128 + lrow * 8 + (quad & 1) * 4;
                *(bf16x4*)&dst[Aoff] = pk;               // 64 lanes -> 512B contiguous
            }
    } else {         // ---- V: normal product (rows=token, r along n); packed V^T store ----
        for (int i = 0; i < 32; i++) {
            const int cur = i & 1;
            __syncthreads();
            if (i < 31) {
                const int k0 = (i + 1) * 32;
                gll(Ap + k0, &As[cur ^ 1][tid * 8]);
                gll(Ap + 64 * 1024 + k0, &As[cur ^ 1][2048 + tid * 8]);
                gll(Bp + k0, &Bs[cur ^ 1][tid * 8]);
                gll(Bp + 64 * 1024 + k0, &Bs[cur ^ 1][2048 + tid * 8]);
            }
            bf16x8 af[4], bfr[4];
#pragma unroll
            for (int ii = 0; ii < 4; ii++) af[ii] = *(const bf16x8*)&As[cur][(wm + ii * 16 + lrow) * 32 + fsw];
#pragma unroll
            for (int j = 0; j < 4; j++) bfr[j] = *(const bf16x8*)&Bs[cur][(wn + j * 16 + lrow) * 32 + fsw];
#pragma unroll
            for (int ii = 0; ii < 4; ii++)
#pragma unroll
                for (int j = 0; j < 4; j++)
                    acc[ii][j] = MFMA16(af[ii], bfr[j], acc[ii][j]);
        }
        // ---- packed store: kpos = i*16 + quad*4 + r; d = j*16 + lrow ----
        const int b = gm0 >> 11;
        const int h = (go0 & 1023) >> 6;
        const long tbase = ((long)(b * 16 + h) * 32 + ((gm0 >> 6) & 31)) * 4096;
#pragma unroll
        for (int i = 0; i < 4; i++)                      // kh = i>>1, n = i&1
#pragma unroll
            for (int j = 0; j < 4; j++) {                // jd = j
                f16x4 pk;
#pragma unroll
                for (int r = 0; r < 4; r++) pk[r] = (f16)acc[i][j][r];
                long Aoff = tbase + (i >> 1) * 2048 + j * 512
                          + (quad * 16 + lrow) * 8 + (i & 1) * 4;
                *(f16x4*)&vo[Aoff] = pk;
            }
    }
}

// ---------------- Flash attention: barrier-free, depth-3 register prefetch ----
// R9 structure (QBLK=128, wave = qh x kh, grid 512, 2 blocks/CU). Each tile's
// 8 coalesced b128 loads now issue TWO compute_tiles (~700cy) before use
// (named A/B/C buffers, x3-unrolled loop -> all static indices). NO LDS, NO
// barriers in main loop. VGPR ~156 (R9: 124 + one more K/V buffer).
__device__ __forceinline__ void load_tile(const bf16* Kt, const f16* Vt, int kh, int lane,
                                          bf16x8 kf[2][2], f16x8 vf[4]) {
#pragma unroll
    for (int ks = 0; ks < 2; ks++)
#pragma unroll
        for (int n = 0; n < 2; n++)
            kf[ks][n] = *(const bf16x8*)&Kt[((kh * 2 + n) * 2 + ks) * 512 + lane * 8];
#pragma unroll
    for (int jd = 0; jd < 4; jd++)
        vf[jd] = *(const f16x8*)&Vt[jd * 512 + lane * 8];
}

__device__ __forceinline__ void compute_tile(const bf16x8 kf[2][2], const f16x8 vf[4],
                                             const bf16x8 qf[4][2],
                                             f32x4 oacc[4][4], float lsum[4]) {
    f32x4 sacc[4][2];
#pragma unroll
    for (int t = 0; t < 4; t++)
#pragma unroll
        for (int n = 0; n < 2; n++) sacc[t][n] = f32x4{-8.f, -8.f, -8.f, -8.f};
    __builtin_amdgcn_s_setprio(1);
#pragma unroll
    for (int ks = 0; ks < 2; ks++)
#pragma unroll
        for (int t = 0; t < 4; t++)
#pragma unroll
            for (int n = 0; n < 2; n++)
                sacc[t][n] = MFMA16(kf[ks][n], qf[t][ks], sacc[t][n]);
    __builtin_amdgcn_s_setprio(0);

    f16x4 pa[4][2];
#pragma unroll
    for (int t = 0; t < 4; t++)
#pragma unroll
        for (int n = 0; n < 2; n++)
#pragma unroll
            for (int r = 0; r < 4; r++) {
                float p = __builtin_exp2f(sacc[t][n][r]);
                lsum[t] += p;
                pa[t][n][r] = (f16)p;
            }

    __builtin_amdgcn_s_setprio(1);
#pragma unroll
    for (int jd = 0; jd < 4; jd++) {
        f16x4 lo = __builtin_shufflevector(vf[jd], vf[jd], 0, 1, 2, 3);   // n=0
        f16x4 hi = __builtin_shufflevector(vf[jd], vf[jd], 4, 5, 6, 7);   // n=1
#pragma unroll
        for (int t = 0; t < 4; t++) {
            oacc[t][jd] = MFMA16F16(pa[t][0], lo, oacc[t][jd]);
            oacc[t][jd] = MFMA16F16(pa[t][1], hi, oacc[t][jd]);
        }
    }
    __builtin_amdgcn_s_setprio(0);
}

__global__ __launch_bounds__(256, 2) void attn_kernel(
    const bf16* __restrict__ qp, const bf16* __restrict__ kp,
    const f16* __restrict__ vp, bf16* __restrict__ o)
{
    __shared__ __align__(16) char smem[35328];   // epilogue Pt (34816) + lsumL (512)

    const int tid = threadIdx.x, wave = tid >> 6, lane = tid & 63;
    const int lrow = lane & 15, quad = lane >> 4;
    const int qh = wave & 1, kh = wave >> 1;
    const int bh = blockIdx.x & 31, qt = blockIdx.x >> 5;   // bh fastest -> XCD-pinned
    const bf16* Qb = qp + ((long)bh * 32 + qt * 2 + qh) * 4096;
    const bf16* Kb = kp + (long)bh * 32 * 4096;
    const f16*  Vb = vp + (long)bh * 32 * 4096 + kh * 2048;

    // Q fragments (64 rows) once
    bf16x8 qf[4][2];
#pragma unroll
    for (int t = 0; t < 4; t++)
#pragma unroll
        for (int ks = 0; ks < 2; ks++)
            qf[t][ks] = *(const bf16x8*)&Qb[(t * 2 + ks) * 512 + lane * 8];

    f32x4 oacc[4][4] = {};
    float lsum[4] = {0.f, 0.f, 0.f, 0.f};

    bf16x8 kA[2][2], kB[2][2], kC[2][2];
    f16x8  vA[4], vB[4], vC[4];
    load_tile(Kb,            Vb,                   kh, lane, kA, vA);   // tile 0
    load_tile(Kb + 4096,     Vb + 4096L,           kh, lane, kB, vB);   // tile 1
    load_tile(Kb + 2 * 4096, Vb + 2 * 4096L,       kh, lane, kC, vC);   // tile 2

    // main: computes tiles t,t+1,t+2; loads t+3,t+4,t+5 (distance = 2 computes)
    for (int t = 0; t < 27; t += 3) {   // t = 0,3,...,24
        compute_tile(kA, vA, qf, oacc, lsum);
        load_tile(Kb + (t + 3) * 4096, Vb + (long)(t + 3) * 4096, kh, lane, kA, vA);
        compute_tile(kB, vB, qf, oacc, lsum);
        load_tile(Kb + (t + 4) * 4096, Vb + (long)(t + 4) * 4096, kh, lane, kB, vB);
        compute_tile(kC, vC, qf, oacc, lsum);
        load_tile(Kb + (t + 5) * 4096, Vb + (long)(t + 5) * 4096, kh, lane, kC, vC);
    }
    // tail: tiles 27..31 (A=27, B=28, C=29 already loaded)
    compute_tile(kA, vA, qf, oacc, lsum);
    load_tile(Kb + 30 * 4096, Vb + 30 * 4096L, kh, lane, kA, vA);
    compute_tile(kB, vB, qf, oacc, lsum);
    load_tile(Kb + 31 * 4096, Vb + 31 * 4096L, kh, lane, kB, vB);
    compute_tile(kC, vC, qf, oacc, lsum);
    compute_tile(kA, vA, qf, oacc, lsum);
    compute_tile(kB, vB, qf, oacc, lsum);

    // ---- in-wave l reduce (across quads) ----
#pragma unroll
    for (int t = 0; t < 4; t++) {
        lsum[t] += __shfl_xor(lsum[t], 16, 64);
        lsum[t] += __shfl_xor(lsum[t], 32, 64);
    }

    // ---- epilogue: combine kh halves ----
    float* Pt  = (float*)smem;                // [2][64*68]
    float* lsL = (float*)(smem + 34816);      // [2][64]
    float* Pr  = Pt + qh * (64 * 68);
    if (kh == 1) {
#pragma unroll
        for (int t = 0; t < 4; t++)
#pragma unroll
            for (int jd = 0; jd < 4; jd++)
                *(f32x4*)&Pr[lane * 68 + (t * 4 + jd) * 4] = oacc[t][jd];
        if (quad == 0)
#pragma unroll
            for (int t = 0; t < 4; t++) lsL[qh * 64 + t * 16 + lrow] = lsum[t];
    }
    __syncthreads();
    if (kh == 0) {
#pragma unroll
        for (int t = 0; t < 4; t++)
#pragma unroll
            for (int jd = 0; jd < 4; jd++)
                oacc[t][jd] += *(const f32x4*)&Pr[lane * 68 + (t * 4 + jd) * 4];
#pragma unroll
        for (int t = 0; t < 4; t++) lsum[t] += lsL[qh * 64 + t * 16 + lrow];

        // transpose-store via Pr reused as bf16 [64][72]
        bf16* Tw = (bf16*)Pr;
        const int b = bh >> 4, h = bh & 15;
#pragma unroll
        for (int t = 0; t < 4; t++) {
            float linv = 1.0f / lsum[t];
#pragma unroll
            for (int r = 0; r < 4; r++) {
                float lr = __shfl(linv, quad * 4 + r, 64);
#pragma unroll
                for (int jd = 0; jd < 4; jd++)
                    Tw[(t * 16 + quad * 4 + r) * 72 + jd * 16 + lrow] = (bf16)(oacc[t][jd][r] * lr);
            }
        }
        const int rr = lane >> 3, cc = (lane & 7) * 8;   // in-wave dep only
#pragma unroll
        for (int p = 0; p < 8; p++) {
            bf16x8 val = *(const bf16x8*)&Tw[(rr + p * 8) * 72 + cc];
            int n = qt * 128 + qh * 64 + rr + p * 8;
            *(bf16x8*)&o[((long)(b * 2048 + n)) * 1024 + h * 64 + cc] = val;
        }
    }
}

// ---------------- GEMM2: 128x64, dbuf, f32x4 stores -----------------------------
__global__ __launch_bounds__(256, 2) void gemm_proj(
    const bf16* __restrict__ A, const bf16* __restrict__ Bm, float* __restrict__ out)
{
    __shared__ bf16 As[2][128 * 32];
    __shared__ bf16 Bs[2][64 * 32];
    const int tid = threadIdx.x;
    const int wave = tid >> 6, lane = tid & 63;
    const int lrow = lane & 15, quad = lane >> 4;
    const int wm = (wave >> 1) * 64, wn = (wave & 1) * 32;
    const int srow = tid >> 2;
    const int scol = ((tid & 3) ^ (srow & 3)) * 8;
    const int fsw = (quad ^ (lrow & 3)) * 8;

    const bf16* Ap = A + (long)(blockIdx.x * 128 + srow) * 1024 + scol;
    const bf16* Bp = Bm + (long)(blockIdx.y * 64 + srow) * 1024 + scol;

    f32x4 acc[4][2] = {};

    gll(Ap, &As[0][tid * 8]);  gll(Ap + 64 * 1024, &As[0][2048 + tid * 8]);
    gll(Bp, &Bs[0][tid * 8]);

    for (int i = 0; i < 32; i++) {
        const int cur = i & 1;
        __syncthreads();
        if (i < 31) {
            const int k0 = (i + 1) * 32;
            gll(Ap + k0, &As[cur ^ 1][tid * 8]);
            gll(Ap + 64 * 1024 + k0, &As[cur ^ 1][2048 + tid * 8]);
            gll(Bp + k0, &Bs[cur ^ 1][tid * 8]);
        }
        bf16x8 af[4], bfr[2];
#pragma unroll
        for (int ii = 0; ii < 4; ii++) af[ii] = *(const bf16x8*)&As[cur][(wm + ii * 16 + lrow) * 32 + fsw];
#pragma unroll
        for (int j = 0; j < 2; j++) bfr[j] = *(const bf16x8*)&Bs[cur][(wn + j * 16 + lrow) * 32 + fsw];
#pragma unroll
        for (int ii = 0; ii < 4; ii++)
#pragma unroll
            for (int j = 0; j < 2; j++)
                acc[ii][j] = MFMA16(bfr[j], af[ii], acc[ii][j]);   // transposed: r along o
    }

    const int gm0 = blockIdx.x * 128 + wm;
    const int go0 = blockIdx.y * 64 + wn;
#pragma unroll
    for (int i = 0; i < 4; i++) {
        int gm = gm0 + i * 16 + lrow;
#pragma unroll
        for (int j = 0; j < 2; j++) {
            int ob = go0 + j * 16 + quad * 4;
            *(f32x4*)&out[(long)gm * 1024 + ob] = acc[i][j];
        }
    }
}

// ---------------- launch ----------------
extern "C" void kernel_launch(void* const* d_in, const int* in_sizes, int n_in,
                              void* d_out, int out_size, void* d_ws, size_t ws_size,
                              hipStream_t stream) {
    const float* x      = (const float*)d_in[0];   // [2,2048,1024]
    const float* w_qkv  = (const float*)d_in[1];   // [3072,1024]
    const float* w_proj = (const float*)d_in[2];   // [1024,1024]
    float* out = (float*)d_out;                    // [2,2048,1024]

    bf16* ws = (bf16*)d_ws;
    bf16* xb     = ws;                       // 4096*1024
    bf16* wqkvb  = xb + 4096 * 1024;         // 3072*1024
    bf16* wprojb = wqkvb + 3072 * 1024;      // 1024*1024
    bf16* qb     = wprojb + 1024 * 1024;     // packed [32][32][8][512] bf16
    bf16* kb     = qb + 2 * 16 * 2048 * 64;  // packed, same size
    f16*  vb     = (f16*)(kb + 2 * 16 * 2048 * 64);  // packed [32][32][2][4][512] f16
    bf16* ob     = (bf16*)(vb + 2 * 16 * 2048 * 64); // 4096*1024 bf16

    cvt_all<<<8192, 256, 0, stream>>>(x, w_qkv, w_proj, xb, wqkvb, wprojb);
    gemm_qkv<<<dim3(32, 24), 256, 0, stream>>>(xb, wqkvb, qb, kb, vb);
    attn_kernel<<<512, 256, 0, stream>>>(qb, kb, vb, ob);
    gemm_proj<<<dim3(32, 16), 256, 0, stream>>>(ob, wprojb, out);
}

// Round 13
// 181.960 us; speedup vs baseline: 2.1791x; 2.1791x over previous
//
#include <hip/hip_runtime.h>
#include <hip/hip_bf16.h>

typedef __bf16 bf16;
typedef __bf16 bf16x8 __attribute__((ext_vector_type(8)));
typedef __bf16 bf16x4 __attribute__((ext_vector_type(4)));
typedef _Float16 f16;
typedef _Float16 f16x4 __attribute__((ext_vector_type(4)));
typedef _Float16 f16x8 __attribute__((ext_vector_type(8)));
typedef float f32x4 __attribute__((ext_vector_type(4)));

#define MFMA16(a, b, c)    __builtin_amdgcn_mfma_f32_16x16x32_bf16(a, b, c, 0, 0, 0)
#define MFMA16F16(a, b, c) __builtin_amdgcn_mfma_f32_16x16x16f16(a, b, c, 0, 0, 0)

// async global->LDS, 16B/lane; LDS dest = wave-uniform base + lane*16.
__device__ __forceinline__ void gll(const void* g, void* l) {
    __builtin_amdgcn_global_load_lds(
        (const __attribute__((address_space(1))) unsigned int*)g,
        (__attribute__((address_space(3))) unsigned int*)l, 16, 0, 0);
}

// ---------------- fused fp32 -> bf16 conversion (one launch) ----------------
__global__ void cvt_all(const float* __restrict__ x, const float* __restrict__ wq,
                        const float* __restrict__ wp, bf16* __restrict__ xb,
                        bf16* __restrict__ wqb, bf16* __restrict__ wpb) {
    int i = blockIdx.x * 256 + threadIdx.x;
    const float4* s; bf16* d; int j;
    if (i < 1048576)                { s = (const float4*)x;  d = xb;  j = i; }
    else if (i < 1048576 + 786432)  { s = (const float4*)wq; d = wqb; j = i - 1048576; }
    else                            { s = (const float4*)wp; d = wpb; j = i - 1835008; }
    float4 f = s[j];
    bf16x4 o; o[0] = (bf16)f.x; o[1] = (bf16)f.y; o[2] = (bf16)f.z; o[3] = (bf16)f.w;
    ((bf16x4*)d)[j] = o;
}

// Q pre-scale: head_dim^-0.5 * log2(e) -> softmax in exp2 domain
#define QSCALE 0.18033688f

// ================= Packed fragment layouts (per (b,h), per 64-token tile) =====
// Q/K (bf16): [tile32][frag8 = nb*2+ks][512 elems]; elem l*8+e of frag =
//   M[nb*16 + (l&15)][ks*32 + (l>>4)*8 + e]  -> attn loads b128 at lane*16B.
// V  (f16):  [tile32][kh2][jd4][512 elems]; elem l*8 + n*4 + c =
//   V^T[jd*16 + (l&15)][kh*32 + n*16 + (l>>4)*4 + c] -> b128 gives n=0/1 halves.

// ---------------- GEMM1: 128x128, dbuf gll; packed-fragment epilogues ---------
__global__ __launch_bounds__(256, 3) void gemm_qkv(
    const bf16* __restrict__ A, const bf16* __restrict__ Bm,
    bf16* __restrict__ qo, bf16* __restrict__ ko, f16* __restrict__ vo)
{
    __shared__ bf16 As[2][128 * 32];
    __shared__ bf16 Bs[2][128 * 32];
    const int tid = threadIdx.x;
    const int wave = tid >> 6, lane = tid & 63;
    const int lrow = lane & 15, quad = lane >> 4;
    const int wm = (wave >> 1) * 64, wn = (wave & 1) * 64;
    const int srow = tid >> 2;
    const int scol = ((tid & 3) ^ (srow & 3)) * 8;
    const int fsw = (quad ^ (lrow & 3)) * 8;

    const bf16* Ap = A + (long)(blockIdx.x * 128 + srow) * 1024 + scol;
    const bf16* Bp = Bm + (long)(blockIdx.y * 128 + srow) * 1024 + scol;

    f32x4 acc[4][4] = {};
    const int gm0 = blockIdx.x * 128 + wm;
    const int go0 = blockIdx.y * 128 + wn;

    gll(Ap, &As[0][tid * 8]);  gll(Ap + 64 * 1024, &As[0][2048 + tid * 8]);
    gll(Bp, &Bs[0][tid * 8]);  gll(Bp + 64 * 1024, &Bs[0][2048 + tid * 8]);

    if (blockIdx.y < 16) {   // ---- Q/K: transposed product (acc reg-index along d) ----
        for (int i = 0; i < 32; i++) {
            const int cur = i & 1;
            __syncthreads();
            if (i < 31) {
                const int k0 = (i + 1) * 32;
                gll(Ap + k0, &As[cur ^ 1][tid * 8]);
                gll(Ap + 64 * 1024 + k0, &As[cur ^ 1][2048 + tid * 8]);
                gll(Bp + k0, &Bs[cur ^ 1][tid * 8]);
                gll(Bp + 64 * 1024 + k0, &Bs[cur ^ 1][2048 + tid * 8]);
            }
            bf16x8 af[4], bfr[4];
#pragma unroll
            for (int ii = 0; ii < 4; ii++) af[ii] = *(const bf16x8*)&As[cur][(wm + ii * 16 + lrow) * 32 + fsw];
#pragma unroll
            for (int j = 0; j < 4; j++) bfr[j] = *(const bf16x8*)&Bs[cur][(wn + j * 16 + lrow) * 32 + fsw];
#pragma unroll
            for (int ii = 0; ii < 4; ii++)
#pragma unroll
                for (int j = 0; j < 4; j++)
                    acc[ii][j] = MFMA16(bfr[j], af[ii], acc[ii][j]);
        }
        // ---- packed store: token range = one tile (64 rows) per wave ----
        const bool isQ = blockIdx.y < 8;
        bf16* dst = isQ ? qo : ko;
        const float sc = isQ ? QSCALE : 1.0f;
        const int b = gm0 >> 11;
        const int h = (go0 & 1023) >> 6;                 // one head per wave (wn=64-aligned)
        const long tbase = ((long)(b * 16 + h) * 32 + ((gm0 >> 6) & 31)) * 4096;
#pragma unroll
        for (int i = 0; i < 4; i++)                      // i = nb (token n-block)
#pragma unroll
            for (int j = 0; j < 4; j++) {                // d = j*16 + quad*4 + r
                bf16x4 pk;
#pragma unroll
                for (int r = 0; r < 4; r++) pk[r] = (bf16)(acc[i][j][r] * sc);
                long Aoff = tbase + (i * 2 + (j >> 1)) * 512
                          + ((j & 1) * 2 + (quad >> 1)) * 128 + lrow * 8 + (quad & 1) * 4;
                *(bf16x4*)&dst[Aoff] = pk;               // 64 lanes -> 512B contiguous
            }
    } else {         // ---- V: normal product (rows=token, r along n); packed V^T store ----
        for (int i = 0; i < 32; i++) {
            const int cur = i & 1;
            __syncthreads();
            if (i < 31) {
                const int k0 = (i + 1) * 32;
                gll(Ap + k0, &As[cur ^ 1][tid * 8]);
                gll(Ap + 64 * 1024 + k0, &As[cur ^ 1][2048 + tid * 8]);
                gll(Bp + k0, &Bs[cur ^ 1][tid * 8]);
                gll(Bp + 64 * 1024 + k0, &Bs[cur ^ 1][2048 + tid * 8]);
            }
            bf16x8 af[4], bfr[4];
#pragma unroll
            for (int ii = 0; ii < 4; ii++) af[ii] = *(const bf16x8*)&As[cur][(wm + ii * 16 + lrow) * 32 + fsw];
#pragma unroll
            for (int j = 0; j < 4; j++) bfr[j] = *(const bf16x8*)&Bs[cur][(wn + j * 16 + lrow) * 32 + fsw];
#pragma unroll
            for (int ii = 0; ii < 4; ii++)
#pragma unroll
                for (int j = 0; j < 4; j++)
                    acc[ii][j] = MFMA16(af[ii], bfr[j], acc[ii][j]);
        }
        // ---- packed store: kpos = i*16 + quad*4 + r; d = j*16 + lrow ----
        const int b = gm0 >> 11;
        const int h = (go0 & 1023) >> 6;
        const long tbase = ((long)(b * 16 + h) * 32 + ((gm0 >> 6) & 31)) * 4096;
#pragma unroll
        for (int i = 0; i < 4; i++)                      // kh = i>>1, n = i&1
#pragma unroll
            for (int j = 0; j < 4; j++) {                // jd = j
                f16x4 pk;
#pragma unroll
                for (int r = 0; r < 4; r++) pk[r] = (f16)acc[i][j][r];
                long Aoff = tbase + (i >> 1) * 2048 + j * 512
                          + (quad * 16 + lrow) * 8 + (i & 1) * 4;
                *(f16x4*)&vo[Aoff] = pk;
            }
    }
}

// ---------------- Flash attention: R9 base + lsum via P*ones MFMA -------------
// Barrier-free, QBLK=128, wave=(qh,kh), grid 512, depth-2 ping-pong (124 VGPR).
// lsum moved off the critical VALU pipe onto the 33%-busy MFMA pipe: 8 tiny
// f16 MFMAs/tile replace 32 v_fmac; ones-MFMA lands rowsum in the SAME lane
// that normalizes that O row (epilogue shuffles deleted).
__device__ __forceinline__ void load_tile(const bf16* Kt, const f16* Vt, int kh, int lane,
                                          bf16x8 kf[2][2], f16x8 vf[4]) {
#pragma unroll
    for (int ks = 0; ks < 2; ks++)
#pragma unroll
        for (int n = 0; n < 2; n++)
            kf[ks][n] = *(const bf16x8*)&Kt[((kh * 2 + n) * 2 + ks) * 512 + lane * 8];
#pragma unroll
    for (int jd = 0; jd < 4; jd++)
        vf[jd] = *(const f16x8*)&Vt[jd * 512 + lane * 8];
}

__device__ __forceinline__ void compute_tile(const bf16x8 kf[2][2], const f16x8 vf[4],
                                             const bf16x8 qf[4][2],
                                             f32x4 oacc[4][4], f32x4 lacc[4]) {
    f32x4 sacc[4][2];
#pragma unroll
    for (int t = 0; t < 4; t++)
#pragma unroll
        for (int n = 0; n < 2; n++) sacc[t][n] = f32x4{-8.f, -8.f, -8.f, -8.f};
    __builtin_amdgcn_s_setprio(1);
#pragma unroll
    for (int ks = 0; ks < 2; ks++)
#pragma unroll
        for (int t = 0; t < 4; t++)
#pragma unroll
            for (int n = 0; n < 2; n++)
                sacc[t][n] = MFMA16(kf[ks][n], qf[t][ks], sacc[t][n]);
    __builtin_amdgcn_s_setprio(0);

    f16x4 pa[4][2];
#pragma unroll
    for (int t = 0; t < 4; t++)
#pragma unroll
        for (int n = 0; n < 2; n++)
#pragma unroll
            for (int r = 0; r < 4; r++)
                pa[t][n][r] = (f16)__builtin_exp2f(sacc[t][n][r]);

    const f16x4 vones = {(f16)1.f, (f16)1.f, (f16)1.f, (f16)1.f};
    __builtin_amdgcn_s_setprio(1);
#pragma unroll
    for (int jd = 0; jd < 4; jd++) {
        f16x4 lo = __builtin_shufflevector(vf[jd], vf[jd], 0, 1, 2, 3);   // n=0
        f16x4 hi = __builtin_shufflevector(vf[jd], vf[jd], 4, 5, 6, 7);   // n=1
#pragma unroll
        for (int t = 0; t < 4; t++) {
            oacc[t][jd] = MFMA16F16(pa[t][0], lo, oacc[t][jd]);
            oacc[t][jd] = MFMA16F16(pa[t][1], hi, oacc[t][jd]);
        }
    }
#pragma unroll
    for (int t = 0; t < 4; t++)
#pragma unroll
        for (int n = 0; n < 2; n++)
            lacc[t] = MFMA16F16(pa[t][n], vones, lacc[t]);   // rowsum -> lane-aligned
    __builtin_amdgcn_s_setprio(0);
}

__global__ __launch_bounds__(256, 2) void attn_kernel(
    const bf16* __restrict__ qp, const bf16* __restrict__ kp,
    const f16* __restrict__ vp, bf16* __restrict__ o)
{
    __shared__ __align__(16) char smem[35328];   // epilogue Pt (34816) + lsumL (512)

    const int tid = threadIdx.x, wave = tid >> 6, lane = tid & 63;
    const int lrow = lane & 15, quad = lane >> 4;
    const int qh = wave & 1, kh = wave >> 1;
    const int bh = blockIdx.x & 31, qt = blockIdx.x >> 5;   // bh fastest -> XCD-pinned
    const bf16* Qb = qp + ((long)bh * 32 + qt * 2 + qh) * 4096;
    const bf16* Kb = kp + (long)bh * 32 * 4096;
    const f16*  Vb = vp + (long)bh * 32 * 4096 + kh * 2048;

    // Q fragments (64 rows) once
    bf16x8 qf[4][2];
#pragma unroll
    for (int t = 0; t < 4; t++)
#pragma unroll
        for (int ks = 0; ks < 2; ks++)
            qf[t][ks] = *(const bf16x8*)&Qb[(t * 2 + ks) * 512 + lane * 8];

    f32x4 oacc[4][4] = {};
    f32x4 lacc[4] = {};

    bf16x8 kA[2][2], kB[2][2];
    f16x8  vA[4], vB[4];
    load_tile(Kb, Vb, kh, lane, kA, vA);                 // tile 0

    for (int kv = 0; kv < 32; kv += 2) {
        load_tile(Kb + (kv + 1) * 4096, Vb + (long)(kv + 1) * 4096, kh, lane, kB, vB);
        compute_tile(kA, vA, qf, oacc, lacc);
        if (kv < 30)
            load_tile(Kb + (kv + 2) * 4096, Vb + (long)(kv + 2) * 4096, kh, lane, kA, vA);
        compute_tile(kB, vB, qf, oacc, lacc);
    }

    // ---- epilogue: combine kh halves (rowsum is lane-local in lacc[t][r]) ----
    float* Pt  = (float*)smem;                // [2][64*68]
    float* lsL = (float*)(smem + 34816);      // [2][64]
    float* Pr  = Pt + qh * (64 * 68);
    if (kh == 1) {
#pragma unroll
        for (int t = 0; t < 4; t++)
#pragma unroll
            for (int jd = 0; jd < 4; jd++)
                *(f32x4*)&Pr[lane * 68 + (t * 4 + jd) * 4] = oacc[t][jd];
        if (lrow == 0)
#pragma unroll
            for (int t = 0; t < 4; t++)
#pragma unroll
                for (int r = 0; r < 4; r++)
                    lsL[qh * 64 + t * 16 + quad * 4 + r] = lacc[t][r];
    }
    __syncthreads();
    if (kh == 0) {
#pragma unroll
        for (int t = 0; t < 4; t++)
#pragma unroll
            for (int jd = 0; jd < 4; jd++)
                oacc[t][jd] += *(const f32x4*)&Pr[lane * 68 + (t * 4 + jd) * 4];

        // normalize: rowsum for q-row (t*16+quad*4+r) is lane-local
        bf16* Tw = (bf16*)Pr;                 // reuse as bf16 [64][72]
        const int b = bh >> 4, h = bh & 15;
#pragma unroll
        for (int t = 0; t < 4; t++) {
#pragma unroll
            for (int r = 0; r < 4; r++) {
                float linv = 1.0f / (lacc[t][r] + lsL[qh * 64 + t * 16 + quad * 4 + r]);
#pragma unroll
                for (int jd = 0; jd < 4; jd++)
                    Tw[(t * 16 + quad * 4 + r) * 72 + jd * 16 + lrow] = (bf16)(oacc[t][jd][r] * linv);
            }
        }
        const int rr = lane >> 3, cc = (lane & 7) * 8;   // in-wave dep only
#pragma unroll
        for (int p = 0; p < 8; p++) {
            bf16x8 val = *(const bf16x8*)&Tw[(rr + p * 8) * 72 + cc];
            int n = qt * 128 + qh * 64 + rr + p * 8;
            *(bf16x8*)&o[((long)(b * 2048 + n)) * 1024 + h * 64 + cc] = val;
        }
    }
}

// ---------------- GEMM2: 128x64, dbuf, f32x4 stores -----------------------------
__global__ __launch_bounds__(256, 2) void gemm_proj(
    const bf16* __restrict__ A, const bf16* __restrict__ Bm, float* __restrict__ out)
{
    __shared__ bf16 As[2][128 * 32];
    __shared__ bf16 Bs[2][64 * 32];
    const int tid = threadIdx.x;
    const int wave = tid >> 6, lane = tid & 63;
    const int lrow = lane & 15, quad = lane >> 4;
    const int wm = (wave >> 1) * 64, wn = (wave & 1) * 32;
    const int srow = tid >> 2;
    const int scol = ((tid & 3) ^ (srow & 3)) * 8;
    const int fsw = (quad ^ (lrow & 3)) * 8;

    const bf16* Ap = A + (long)(blockIdx.x * 128 + srow) * 1024 + scol;
    const bf16* Bp = Bm + (long)(blockIdx.y * 64 + srow) * 1024 + scol;

    f32x4 acc[4][2] = {};

    gll(Ap, &As[0][tid * 8]);  gll(Ap + 64 * 1024, &As[0][2048 + tid * 8]);
    gll(Bp, &Bs[0][tid * 8]);

    for (int i = 0; i < 32; i++) {
        const int cur = i & 1;
        __syncthreads();
        if (i < 31) {
            const int k0 = (i + 1) * 32;
            gll(Ap + k0, &As[cur ^ 1][tid * 8]);
            gll(Ap + 64 * 1024 + k0, &As[cur ^ 1][2048 + tid * 8]);
            gll(Bp + k0, &Bs[cur ^ 1][tid * 8]);
        }
        bf16x8 af[4], bfr[2];
#pragma unroll
        for (int ii = 0; ii < 4; ii++) af[ii] = *(const bf16x8*)&As[cur][(wm + ii * 16 + lrow) * 32 + fsw];
#pragma unroll
        for (int j = 0; j < 2; j++) bfr[j] = *(const bf16x8*)&Bs[cur][(wn + j * 16 + lrow) * 32 + fsw];
#pragma unroll
        for (int ii = 0; ii < 4; ii++)
#pragma unroll
            for (int j = 0; j < 2; j++)
                acc[ii][j] = MFMA16(bfr[j], af[ii], acc[ii][j]);   // transposed: r along o
    }

    const int gm0 = blockIdx.x * 128 + wm;
    const int go0 = blockIdx.y * 64 + wn;
#pragma unroll
    for (int i = 0; i < 4; i++) {
        int gm = gm0 + i * 16 + lrow;
#pragma unroll
        for (int j = 0; j < 2; j++) {
            int ob = go0 + j * 16 + quad * 4;
            *(f32x4*)&out[(long)gm * 1024 + ob] = acc[i][j];
        }
    }
}

// ---------------- launch ----------------
extern "C" void kernel_launch(void* const* d_in, const int* in_sizes, int n_in,
                              void* d_out, int out_size, void* d_ws, size_t ws_size,
                              hipStream_t stream) {
    const float* x      = (const float*)d_in[0];   // [2,2048,1024]
    const float* w_qkv  = (const float*)d_in[1];   // [3072,1024]
    const float* w_proj = (const float*)d_in[2];   // [1024,1024]
    float* out = (float*)d_out;                    // [2,2048,1024]

    bf16* ws = (bf16*)d_ws;
    bf16* xb     = ws;                       // 4096*1024
    bf16* wqkvb  = xb + 4096 * 1024;         // 3072*1024
    bf16* wprojb = wqkvb + 3072 * 1024;      // 1024*1024
    bf16* qb     = wprojb + 1024 * 1024;     // packed [32][32][8][512] bf16
    bf16* kb     = qb + 2 * 16 * 2048 * 64;  // packed, same size
    f16*  vb     = (f16*)(kb + 2 * 16 * 2048 * 64);  // packed [32][32][2][4][512] f16
    bf16* ob     = (bf16*)(vb + 2 * 16 * 2048 * 64); // 4096*1024 bf16

    cvt_all<<<8192, 256, 0, stream>>>(x, w_qkv, w_proj, xb, wqkvb, wprojb);
    gemm_qkv<<<dim3(32, 24), 256, 0, stream>>>(xb, wqkvb, qb, kb, vb);
    attn_kernel<<<512, 256, 0, stream>>>(qb, kb, vb, ob);
    gemm_proj<<<dim3(32, 16), 256, 0, stream>>>(ob, wprojb, out);
}

// Round 15
// 170.966 us; speedup vs baseline: 2.3192x; 1.0643x over previous
//
#include <hip/hip_runtime.h>
#include <hip/hip_bf16.h>

typedef __bf16 bf16;
typedef __bf16 bf16x8 __attribute__((ext_vector_type(8)));
typedef __bf16 bf16x4 __attribute__((ext_vector_type(4)));
typedef _Float16 f16;
typedef _Float16 f16x2 __attribute__((ext_vector_type(2)));
typedef __fp16 hf16x2 __attribute__((ext_vector_type(2)));
typedef _Float16 f16x4 __attribute__((ext_vector_type(4)));
typedef _Float16 f16x8 __attribute__((ext_vector_type(8)));
typedef float f32x4 __attribute__((ext_vector_type(4)));

#define MFMA16(a, b, c)    __builtin_amdgcn_mfma_f32_16x16x32_bf16(a, b, c, 0, 0, 0)
#define MFMA16F16(a, b, c) __builtin_amdgcn_mfma_f32_16x16x16f16(a, b, c, 0, 0, 0)

// async global->LDS, 16B/lane; LDS dest = wave-uniform base + lane*16.
__device__ __forceinline__ void gll(const void* g, void* l) {
    __builtin_amdgcn_global_load_lds(
        (const __attribute__((address_space(1))) unsigned int*)g,
        (__attribute__((address_space(3))) unsigned int*)l, 16, 0, 0);
}

// ---------------- fused fp32 -> bf16 conversion (one launch) ----------------
__global__ void cvt_all(const float* __restrict__ x, const float* __restrict__ wq,
                        const float* __restrict__ wp, bf16* __restrict__ xb,
                        bf16* __restrict__ wqb, bf16* __restrict__ wpb) {
    int i = blockIdx.x * 256 + threadIdx.x;
    const float4* s; bf16* d; int j;
    if (i < 1048576)                { s = (const float4*)x;  d = xb;  j = i; }
    else if (i < 1048576 + 786432)  { s = (const float4*)wq; d = wqb; j = i - 1048576; }
    else                            { s = (const float4*)wp; d = wpb; j = i - 1835008; }
    float4 f = s[j];
    bf16x4 o; o[0] = (bf16)f.x; o[1] = (bf16)f.y; o[2] = (bf16)f.z; o[3] = (bf16)f.w;
    ((bf16x4*)d)[j] = o;
}

// Q pre-scale: head_dim^-0.5 * log2(e) -> softmax in exp2 domain
#define QSCALE 0.18033688f

// ================= Packed fragment layouts (per (b,h), per 64-token tile) =====
// Q/K (bf16): [tile32][frag8 = nb*2+ks][512 elems]; elem l*8+e of frag =
//   M[nb*16 + (l&15)][ks*32 + (l>>4)*8 + e]  -> attn loads b128 at lane*16B.
// V  (f16):  [tile32][kh2][jd4][512 elems]; elem l*8 + n*4 + c =
//   V^T[jd*16 + (l&15)][kh*32 + n*16 + (l>>4)*4 + c] -> b128 gives n=0/1 halves.

// ---------------- GEMM1: 128x128, dbuf gll; packed-fragment epilogues ---------
__global__ __launch_bounds__(256, 3) void gemm_qkv(
    const bf16* __restrict__ A, const bf16* __restrict__ Bm,
    bf16* __restrict__ qo, bf16* __restrict__ ko, f16* __restrict__ vo)
{
    __shared__ bf16 As[2][128 * 32];
    __shared__ bf16 Bs[2][128 * 32];
    const int tid = threadIdx.x;
    const int wave = tid >> 6, lane = tid & 63;
    const int lrow = lane & 15, quad = lane >> 4;
    const int wm = (wave >> 1) * 64, wn = (wave & 1) * 64;
    const int srow = tid >> 2;
    const int scol = ((tid & 3) ^ (srow & 3)) * 8;
    const int fsw = (quad ^ (lrow & 3)) * 8;

    const bf16* Ap = A + (long)(blockIdx.x * 128 + srow) * 1024 + scol;
    const bf16* Bp = Bm + (long)(blockIdx.y * 128 + srow) * 1024 + scol;

    f32x4 acc[4][4] = {};
    const int gm0 = blockIdx.x * 128 + wm;
    const int go0 = blockIdx.y * 128 + wn;

    gll(Ap, &As[0][tid * 8]);  gll(Ap + 64 * 1024, &As[0][2048 + tid * 8]);
    gll(Bp, &Bs[0][tid * 8]);  gll(Bp + 64 * 1024, &Bs[0][2048 + tid * 8]);

    if (blockIdx.y < 16) {   // ---- Q/K: transposed product (acc reg-index along d) ----
        for (int i = 0; i < 32; i++) {
            const int cur = i & 1;
            __syncthreads();
            if (i < 31) {
                const int k0 = (i + 1) * 32;
                gll(Ap + k0, &As[cur ^ 1][tid * 8]);
                gll(Ap + 64 * 1024 + k0, &As[cur ^ 1][2048 + tid * 8]);
                gll(Bp + k0, &Bs[cur ^ 1][tid * 8]);
                gll(Bp + 64 * 1024 + k0, &Bs[cur ^ 1][2048 + tid * 8]);
            }
            bf16x8 af[4], bfr[4];
#pragma unroll
            for (int ii = 0; ii < 4; ii++) af[ii] = *(const bf16x8*)&As[cur][(wm + ii * 16 + lrow) * 32 + fsw];
#pragma unroll
            for (int j = 0; j < 4; j++) bfr[j] = *(const bf16x8*)&Bs[cur][(wn + j * 16 + lrow) * 32 + fsw];
#pragma unroll
            for (int ii = 0; ii < 4; ii++)
#pragma unroll
                for (int j = 0; j < 4; j++)
                    acc[ii][j] = MFMA16(bfr[j], af[ii], acc[ii][j]);
        }
        // ---- packed store: token range = one tile (64 rows) per wave ----
        const bool isQ = blockIdx.y < 8;
        bf16* dst = isQ ? qo : ko;
        const float sc = isQ ? QSCALE : 1.0f;
        const int b = gm0 >> 11;
        const int h = (go0 & 1023) >> 6;                 // one head per wave (wn=64-aligned)
        const long tbase = ((long)(b * 16 + h) * 32 + ((gm0 >> 6) & 31)) * 4096;
#pragma unroll
        for (int i = 0; i < 4; i++)                      // i = nb (token n-block)
#pragma unroll
            for (int j = 0; j < 4; j++) {                // d = j*16 + quad*4 + r
                bf16x4 pk;
#pragma unroll
                for (int r = 0; r < 4; r++) pk[r] = (bf16)(acc[i][j][r] * sc);
                long Aoff = tbase + (i * 2 + (j >> 1)) * 512
                          + ((j & 1) * 2 + (quad >> 1)) * 128 + lrow * 8 + (quad & 1) * 4;
                *(bf16x4*)&dst[Aoff] = pk;               // 64 lanes -> 512B contiguous
            }
    } else {         // ---- V: normal product (rows=token, r along n); packed V^T store ----
        for (int i = 0; i < 32; i++) {
            const int cur = i & 1;
            __syncthreads();
            if (i < 31) {
                const int k0 = (i + 1) * 32;
                gll(Ap + k0, &As[cur ^ 1][tid * 8]);
                gll(Ap + 64 * 1024 + k0, &As[cur ^ 1][2048 + tid * 8]);
                gll(Bp + k0, &Bs[cur ^ 1][tid * 8]);
                gll(Bp + 64 * 1024 + k0, &Bs[cur ^ 1][2048 + tid * 8]);
            }
            bf16x8 af[4], bfr[4];
#pragma unroll
            for (int ii = 0; ii < 4; ii++) af[ii] = *(const bf16x8*)&As[cur][(wm + ii * 16 + lrow) * 32 + fsw];
#pragma unroll
            for (int j = 0; j < 4; j++) bfr[j] = *(const bf16x8*)&Bs[cur][(wn + j * 16 + lrow) * 32 + fsw];
#pragma unroll
            for (int ii = 0; ii < 4; ii++)
#pragma unroll
                for (int j = 0; j < 4; j++)
                    acc[ii][j] = MFMA16(af[ii], bfr[j], acc[ii][j]);
        }
        // ---- packed store: kpos = i*16 + quad*4 + r; d = j*16 + lrow ----
        const int b = gm0 >> 11;
        const int h = (go0 & 1023) >> 6;
        const long tbase = ((long)(b * 16 + h) * 32 + ((gm0 >> 6) & 31)) * 4096;
#pragma unroll
        for (int i = 0; i < 4; i++)                      // kh = i>>1, n = i&1
#pragma unroll
            for (int j = 0; j < 4; j++) {                // jd = j
                f16x4 pk;
#pragma unroll
                for (int r = 0; r < 4; r++) pk[r] = (f16)acc[i][j][r];
                long Aoff = tbase + (i >> 1) * 2048 + j * 512
                          + (quad * 16 + lrow) * 8 + (i & 1) * 4;
                *(f16x4*)&vo[Aoff] = pk;
            }
    }
}

// ---------------- Flash attention: R9 base + VALU-trimmed softmax -------------
// Barrier-free, QBLK=128, wave=(qh,kh), grid 512, depth-2 ping-pong.
// Softmax VALU cut: native v_exp via __builtin_amdgcn_exp2f (bypass ocml path),
// f32->f16 packing via v_cvt_pkrtz (16 insts vs ~48), tree-structured lsum.
__device__ __forceinline__ void load_tile(const bf16* Kt, const f16* Vt, int kh, int lane,
                                          bf16x8 kf[2][2], f16x8 vf[4]) {
#pragma unroll
    for (int ks = 0; ks < 2; ks++)
#pragma unroll
        for (int n = 0; n < 2; n++)
            kf[ks][n] = *(const bf16x8*)&Kt[((kh * 2 + n) * 2 + ks) * 512 + lane * 8];
#pragma unroll
    for (int jd = 0; jd < 4; jd++)
        vf[jd] = *(const f16x8*)&Vt[jd * 512 + lane * 8];
}

__device__ __forceinline__ void compute_tile(const bf16x8 kf[2][2], const f16x8 vf[4],
                                             const bf16x8 qf[4][2],
                                             f32x4 oacc[4][4], float lsum[4]) {
    f32x4 sacc[4][2];
#pragma unroll
    for (int t = 0; t < 4; t++)
#pragma unroll
        for (int n = 0; n < 2; n++) sacc[t][n] = f32x4{-8.f, -8.f, -8.f, -8.f};
    __builtin_amdgcn_s_setprio(1);
#pragma unroll
    for (int ks = 0; ks < 2; ks++)
#pragma unroll
        for (int t = 0; t < 4; t++)
#pragma unroll
            for (int n = 0; n < 2; n++)
                sacc[t][n] = MFMA16(kf[ks][n], qf[t][ks], sacc[t][n]);
    __builtin_amdgcn_s_setprio(0);

    f16x4 pa[4][2];
#pragma unroll
    for (int t = 0; t < 4; t++)
#pragma unroll
        for (int n = 0; n < 2; n++) {
            float p0 = __builtin_amdgcn_exp2f(sacc[t][n][0]);
            float p1 = __builtin_amdgcn_exp2f(sacc[t][n][1]);
            float p2 = __builtin_amdgcn_exp2f(sacc[t][n][2]);
            float p3 = __builtin_amdgcn_exp2f(sacc[t][n][3]);
            lsum[t] += (p0 + p1) + (p2 + p3);
            f16x2 l2 = __builtin_bit_cast(f16x2, __builtin_amdgcn_cvt_pkrtz(p0, p1));
            f16x2 h2 = __builtin_bit_cast(f16x2, __builtin_amdgcn_cvt_pkrtz(p2, p3));
            pa[t][n][0] = l2[0]; pa[t][n][1] = l2[1];
            pa[t][n][2] = h2[0]; pa[t][n][3] = h2[1];
        }

    __builtin_amdgcn_s_setprio(1);
#pragma unroll
    for (int jd = 0; jd < 4; jd++) {
        f16x4 lo = __builtin_shufflevector(vf[jd], vf[jd], 0, 1, 2, 3);   // n=0
        f16x4 hi = __builtin_shufflevector(vf[jd], vf[jd], 4, 5, 6, 7);   // n=1
#pragma unroll
        for (int t = 0; t < 4; t++) {
            oacc[t][jd] = MFMA16F16(pa[t][0], lo, oacc[t][jd]);
            oacc[t][jd] = MFMA16F16(pa[t][1], hi, oacc[t][jd]);
        }
    }
    __builtin_amdgcn_s_setprio(0);
}

__global__ __launch_bounds__(256, 2) void attn_kernel(
    const bf16* __restrict__ qp, const bf16* __restrict__ kp,
    const f16* __restrict__ vp, bf16* __restrict__ o)
{
    __shared__ __align__(16) char smem[35328];   // epilogue Pt (34816) + lsumL (512)

    const int tid = threadIdx.x, wave = tid >> 6, lane = tid & 63;
    const int lrow = lane & 15, quad = lane >> 4;
    const int qh = wave & 1, kh = wave >> 1;
    const int bh = blockIdx.x & 31, qt = blockIdx.x >> 5;   // bh fastest -> XCD-pinned
    const bf16* Qb = qp + ((long)bh * 32 + qt * 2 + qh) * 4096;
    const bf16* Kb = kp + (long)bh * 32 * 4096;
    const f16*  Vb = vp + (long)bh * 32 * 4096 + kh * 2048;

    // Q fragments (64 rows) once
    bf16x8 qf[4][2];
#pragma unroll
    for (int t = 0; t < 4; t++)
#pragma unroll
        for (int ks = 0; ks < 2; ks++)
            qf[t][ks] = *(const bf16x8*)&Qb[(t * 2 + ks) * 512 + lane * 8];

    f32x4 oacc[4][4] = {};
    float lsum[4] = {0.f, 0.f, 0.f, 0.f};

    bf16x8 kA[2][2], kB[2][2];
    f16x8  vA[4], vB[4];
    load_tile(Kb, Vb, kh, lane, kA, vA);                 // tile 0

    for (int kv = 0; kv < 32; kv += 2) {
        load_tile(Kb + (kv + 1) * 4096, Vb + (long)(kv + 1) * 4096, kh, lane, kB, vB);
        compute_tile(kA, vA, qf, oacc, lsum);
        if (kv < 30)
            load_tile(Kb + (kv + 2) * 4096, Vb + (long)(kv + 2) * 4096, kh, lane, kA, vA);
        compute_tile(kB, vB, qf, oacc, lsum);
    }

    // ---- in-wave l reduce (across quads) ----
#pragma unroll
    for (int t = 0; t < 4; t++) {
        lsum[t] += __shfl_xor(lsum[t], 16, 64);
        lsum[t] += __shfl_xor(lsum[t], 32, 64);
    }

    // ---- epilogue: combine kh halves ----
    float* Pt  = (float*)smem;                // [2][64*68]
    float* lsL = (float*)(smem + 34816);      // [2][64]
    float* Pr  = Pt + qh * (64 * 68);
    if (kh == 1) {
#pragma unroll
        for (int t = 0; t < 4; t++)
#pragma unroll
            for (int jd = 0; jd < 4; jd++)
                *(f32x4*)&Pr[lane * 68 + (t * 4 + jd) * 4] = oacc[t][jd];
        if (quad == 0)
#pragma unroll
            for (int t = 0; t < 4; t++) lsL[qh * 64 + t * 16 + lrow] = lsum[t];
    }
    __syncthreads();
    if (kh == 0) {
#pragma unroll
        for (int t = 0; t < 4; t++)
#pragma unroll
            for (int jd = 0; jd < 4; jd++)
                oacc[t][jd] += *(const f32x4*)&Pr[lane * 68 + (t * 4 + jd) * 4];
#pragma unroll
        for (int t = 0; t < 4; t++) lsum[t] += lsL[qh * 64 + t * 16 + lrow];

        // transpose-store via Pr reused as bf16 [64][72]
        bf16* Tw = (bf16*)Pr;
        const int b = bh >> 4, h = bh & 15;
#pragma unroll
        for (int t = 0; t < 4; t++) {
            float linv = 1.0f / lsum[t];
#pragma unroll
            for (int r = 0; r < 4; r++) {
                float lr = __shfl(linv, quad * 4 + r, 64);
#pragma unroll
                for (int jd = 0; jd < 4; jd++)
                    Tw[(t * 16 + quad * 4 + r) * 72 + jd * 16 + lrow] = (bf16)(oacc[t][jd][r] * lr);
            }
        }
        const int rr = lane >> 3, cc = (lane & 7) * 8;   // in-wave dep only
#pragma unroll
        for (int p = 0; p < 8; p++) {
            bf16x8 val = *(const bf16x8*)&Tw[(rr + p * 8) * 72 + cc];
            int n = qt * 128 + qh * 64 + rr + p * 8;
            *(bf16x8*)&o[((long)(b * 2048 + n)) * 1024 + h * 64 + cc] = val;
        }
    }
}

// ---------------- GEMM2: 128x64, dbuf, f32x4 stores -----------------------------
__global__ __launch_bounds__(256, 2) void gemm_proj(
    const bf16* __restrict__ A, const bf16* __restrict__ Bm, float* __restrict__ out)
{
    __shared__ bf16 As[2][128 * 32];
    __shared__ bf16 Bs[2][64 * 32];
    const int tid = threadIdx.x;
    const int wave = tid >> 6, lane = tid & 63;
    const int lrow = lane & 15, quad = lane >> 4;
    const int wm = (wave >> 1) * 64, wn = (wave & 1) * 32;
    const int srow = tid >> 2;
    const int scol = ((tid & 3) ^ (srow & 3)) * 8;
    const int fsw = (quad ^ (lrow & 3)) * 8;

    const bf16* Ap = A + (long)(blockIdx.x * 128 + srow) * 1024 + scol;
    const bf16* Bp = Bm + (long)(blockIdx.y * 64 + srow) * 1024 + scol;

    f32x4 acc[4][2] = {};

    gll(Ap, &As[0][tid * 8]);  gll(Ap + 64 * 1024, &As[0][2048 + tid * 8]);
    gll(Bp, &Bs[0][tid * 8]);

    for (int i = 0; i < 32; i++) {
        const int cur = i & 1;
        __syncthreads();
        if (i < 31) {
            const int k0 = (i + 1) * 32;
            gll(Ap + k0, &As[cur ^ 1][tid * 8]);
            gll(Ap + 64 * 1024 + k0, &As[cur ^ 1][2048 + tid * 8]);
            gll(Bp + k0, &Bs[cur ^ 1][tid * 8]);
        }
        bf16x8 af[4], bfr[2];
#pragma unroll
        for (int ii = 0; ii < 4; ii++) af[ii] = *(const bf16x8*)&As[cur][(wm + ii * 16 + lrow) * 32 + fsw];
#pragma unroll
        for (int j = 0; j < 2; j++) bfr[j] = *(const bf16x8*)&Bs[cur][(wn + j * 16 + lrow) * 32 + fsw];
#pragma unroll
        for (int ii = 0; ii < 4; ii++)
#pragma unroll
            for (int j = 0; j < 2; j++)
                acc[ii][j] = MFMA16(bfr[j], af[ii], acc[ii][j]);   // transposed: r along o
    }

    const int gm0 = blockIdx.x * 128 + wm;
    const int go0 = blockIdx.y * 64 + wn;
#pragma unroll
    for (int i = 0; i < 4; i++) {
        int gm = gm0 + i * 16 + lrow;
#pragma unroll
        for (int j = 0; j < 2; j++) {
            int ob = go0 + j * 16 + quad * 4;
            *(f32x4*)&out[(long)gm * 1024 + ob] = acc[i][j];
        }
    }
}

// ---------------- launch ----------------
extern "C" void kernel_launch(void* const* d_in, const int* in_sizes, int n_in,
                              void* d_out, int out_size, void* d_ws, size_t ws_size,
                              hipStream_t stream) {
    const float* x      = (const float*)d_in[0];   // [2,2048,1024]
    const float* w_qkv  = (const float*)d_in[1];   // [3072,1024]
    const float* w_proj = (const float*)d_in[2];   // [1024,1024]
    float* out = (float*)d_out;                    // [2,2048,1024]

    bf16* ws = (bf16*)d_ws;
    bf16* xb     = ws;                       // 4096*1024
    bf16* wqkvb  = xb + 4096 * 1024;         // 3072*1024
    bf16* wprojb = wqkvb + 3072 * 1024;      // 1024*1024
    bf16* qb     = wprojb + 1024 * 1024;     // packed [32][32][8][512] bf16
    bf16* kb     = qb + 2 * 16 * 2048 * 64;  // packed, same size
    f16*  vb     = (f16*)(kb + 2 * 16 * 2048 * 64);  // packed [32][32][2][4][512] f16
    bf16* ob     = (bf16*)(vb + 2 * 16 * 2048 * 64); // 4096*1024 bf16

    cvt_all<<<8192, 256, 0, stream>>>(x, w_qkv, w_proj, xb, wqkvb, wprojb);
    gemm_qkv<<<dim3(32, 24), 256, 0, stream>>>(xb, wqkvb, qb, kb, vb);
    attn_kernel<<<512, 256, 0, stream>>>(qb, kb, vb, ob);
    gemm_proj<<<dim3(32, 16), 256, 0, stream>>>(ob, wprojb, out);
}

// Round 16
// 166.058 us; speedup vs baseline: 2.3877x; 1.0296x over previous
//
#include <hip/hip_runtime.h>
#include <hip/hip_bf16.h>

typedef __bf16 bf16;
typedef __bf16 bf16x8 __attribute__((ext_vector_type(8)));
typedef __bf16 bf16x4 __attribute__((ext_vector_type(4)));
typedef _Float16 f16;
typedef _Float16 f16x4 __attribute__((ext_vector_type(4)));
typedef _Float16 f16x8 __attribute__((ext_vector_type(8)));
typedef float f32x4 __attribute__((ext_vector_type(4)));
typedef unsigned int u32;
typedef unsigned int u32x4 __attribute__((ext_vector_type(4)));

#define MFMA16(a, b, c)     __builtin_amdgcn_mfma_f32_16x16x32_bf16(a, b, c, 0, 0, 0)
#define MFMAF16X32(a, b, c) __builtin_amdgcn_mfma_f32_16x16x32_f16(a, b, c, 0, 0, 0)

// async global->LDS, 16B/lane; LDS dest = wave-uniform base + lane*16.
__device__ __forceinline__ void gll(const void* g, void* l) {
    __builtin_amdgcn_global_load_lds(
        (const __attribute__((address_space(1))) unsigned int*)g,
        (__attribute__((address_space(3))) unsigned int*)l, 16, 0, 0);
}

// ---------------- fused fp32 -> bf16 conversion (one launch) ----------------
__global__ void cvt_all(const float* __restrict__ x, const float* __restrict__ wq,
                        const float* __restrict__ wp, bf16* __restrict__ xb,
                        bf16* __restrict__ wqb, bf16* __restrict__ wpb) {
    int i = blockIdx.x * 256 + threadIdx.x;
    const float4* s; bf16* d; int j;
    if (i < 1048576)                { s = (const float4*)x;  d = xb;  j = i; }
    else if (i < 1048576 + 786432)  { s = (const float4*)wq; d = wqb; j = i - 1048576; }
    else                            { s = (const float4*)wp; d = wpb; j = i - 1835008; }
    float4 f = s[j];
    bf16x4 o; o[0] = (bf16)f.x; o[1] = (bf16)f.y; o[2] = (bf16)f.z; o[3] = (bf16)f.w;
    ((bf16x4*)d)[j] = o;
}

// Q pre-scale: head_dim^-0.5 * log2(e) -> softmax in exp2 domain
#define QSCALE 0.18033688f

// ================= Packed fragment layouts (per (b,h), per 64-token tile) =====
// Q (bf16): [tile32][frag8 = nb*2+ks][512]; elem l*8+e = Q[nb*16+(l&15)][ks*32+(l>>4)*8+e].
// K (bf16): same frag shape, but keys PERMUTED within each 32-key half:
//   physical key krem (0..31) stored at block n=(krem>>2)&1, row m=((krem>>3)<<2)|(krem&3)
//   -> QK output lane then holds keys quad*8+{0..7} = x32-f16 A-frag order.
// V (f16): [tile32][kh2][jd4][512]; elem l*8+e = V^T[jd*16+(l&15)][kh*32+(l>>4)*8+e]
//   (k-dim indexes physical keys -> matches PV x32 B-frag directly).

// ---------------- GEMM1: 128x128, dbuf gll; packed-fragment epilogues ---------
__global__ __launch_bounds__(256, 3) void gemm_qkv(
    const bf16* __restrict__ A, const bf16* __restrict__ Bm,
    bf16* __restrict__ qo, bf16* __restrict__ ko, f16* __restrict__ vo)
{
    __shared__ bf16 As[2][128 * 32];
    __shared__ bf16 Bs[2][128 * 32];
    const int tid = threadIdx.x;
    const int wave = tid >> 6, lane = tid & 63;
    const int lrow = lane & 15, quad = lane >> 4;
    const int wm = (wave >> 1) * 64, wn = (wave & 1) * 64;
    const int srow = tid >> 2;
    const int scol = ((tid & 3) ^ (srow & 3)) * 8;
    const int fsw = (quad ^ (lrow & 3)) * 8;

    const bf16* Ap = A + (long)(blockIdx.x * 128 + srow) * 1024 + scol;
    const bf16* Bp = Bm + (long)(blockIdx.y * 128 + srow) * 1024 + scol;

    f32x4 acc[4][4] = {};
    const int gm0 = blockIdx.x * 128 + wm;
    const int go0 = blockIdx.y * 128 + wn;

    gll(Ap, &As[0][tid * 8]);  gll(Ap + 64 * 1024, &As[0][2048 + tid * 8]);
    gll(Bp, &Bs[0][tid * 8]);  gll(Bp + 64 * 1024, &Bs[0][2048 + tid * 8]);

    if (blockIdx.y < 16) {   // ---- Q/K: transposed product (acc reg-index along d) ----
        for (int i = 0; i < 32; i++) {
            const int cur = i & 1;
            __syncthreads();
            if (i < 31) {
                const int k0 = (i + 1) * 32;
                gll(Ap + k0, &As[cur ^ 1][tid * 8]);
                gll(Ap + 64 * 1024 + k0, &As[cur ^ 1][2048 + tid * 8]);
                gll(Bp + k0, &Bs[cur ^ 1][tid * 8]);
                gll(Bp + 64 * 1024 + k0, &Bs[cur ^ 1][2048 + tid * 8]);
            }
            bf16x8 af[4], bfr[4];
#pragma unroll
            for (int ii = 0; ii < 4; ii++) af[ii] = *(const bf16x8*)&As[cur][(wm + ii * 16 + lrow) * 32 + fsw];
#pragma unroll
            for (int j = 0; j < 4; j++) bfr[j] = *(const bf16x8*)&Bs[cur][(wn + j * 16 + lrow) * 32 + fsw];
#pragma unroll
            for (int ii = 0; ii < 4; ii++)
#pragma unroll
                for (int j = 0; j < 4; j++)
                    acc[ii][j] = MFMA16(bfr[j], af[ii], acc[ii][j]);
        }
        // ---- packed store (wave = 64 tokens x one head) ----
        const bool isQ = blockIdx.y < 8;
        bf16* dst = isQ ? qo : ko;
        const float sc = isQ ? QSCALE : 1.0f;
        const int b = gm0 >> 11;
        const int h = (go0 & 1023) >> 6;
        const long tbase = ((long)(b * 16 + h) * 32 + ((gm0 >> 6) & 31)) * 4096;
        // K permutation pieces (depend on lrow/i only)
        const int kn = (lrow >> 2) & 1;                       // key bit2 -> block n
        const int kmBase = (lrow >> 3) * 4 + (lrow & 3);      // m without i contribution
#pragma unroll
        for (int i = 0; i < 4; i++)                           // i = token n-block
#pragma unroll
            for (int j = 0; j < 4; j++) {                     // d = j*16 + quad*4 + r
                bf16x4 pk;
#pragma unroll
                for (int r = 0; r < 4; r++) pk[r] = (bf16)(acc[i][j][r] * sc);
                long Aoff;
                if (isQ) {
                    Aoff = tbase + (i * 2 + (j >> 1)) * 512
                         + ((j & 1) * 2 + (quad >> 1)) * 128 + lrow * 8 + (quad & 1) * 4;
                } else {
                    const int m = (i & 1) * 8 + kmBase;       // permuted A-row
                    Aoff = tbase + (((i >> 1) * 2 + kn) * 2 + (j >> 1)) * 512
                         + ((j & 1) * 2 + (quad >> 1)) * 128 + m * 8 + (quad & 1) * 4;
                }
                *(bf16x4*)&dst[Aoff] = pk;
            }
    } else {         // ---- V: normal product (rows=token, r along n); packed V^T store ----
        for (int i = 0; i < 32; i++) {
            const int cur = i & 1;
            __syncthreads();
            if (i < 31) {
                const int k0 = (i + 1) * 32;
                gll(Ap + k0, &As[cur ^ 1][tid * 8]);
                gll(Ap + 64 * 1024 + k0, &As[cur ^ 1][2048 + tid * 8]);
                gll(Bp + k0, &Bs[cur ^ 1][tid * 8]);
                gll(Bp + 64 * 1024 + k0, &Bs[cur ^ 1][2048 + tid * 8]);
            }
            bf16x8 af[4], bfr[4];
#pragma unroll
            for (int ii = 0; ii < 4; ii++) af[ii] = *(const bf16x8*)&As[cur][(wm + ii * 16 + lrow) * 32 + fsw];
#pragma unroll
            for (int j = 0; j < 4; j++) bfr[j] = *(const bf16x8*)&Bs[cur][(wn + j * 16 + lrow) * 32 + fsw];
#pragma unroll
            for (int ii = 0; ii < 4; ii++)
#pragma unroll
                for (int j = 0; j < 4; j++)
                    acc[ii][j] = MFMA16(af[ii], bfr[j], acc[ii][j]);
        }
        // ---- packed store: key = i*16 + quad*4 + r; d = j*16 + lrow ----
        const int b = gm0 >> 11;
        const int h = (go0 & 1023) >> 6;
        const long tbase = ((long)(b * 16 + h) * 32 + ((gm0 >> 6) & 31)) * 4096;
#pragma unroll
        for (int i = 0; i < 4; i++)
#pragma unroll
            for (int j = 0; j < 4; j++) {
                f16x4 pk;
#pragma unroll
                for (int r = 0; r < 4; r++) pk[r] = (f16)acc[i][j][r];
                long Aoff = tbase + (i >> 1) * 2048 + j * 512
                          + ((i & 1) * 2 + (quad >> 1)) * 128 + lrow * 8 + (quad & 1) * 4;
                *(f16x4*)&vo[Aoff] = pk;
            }
    }
}

// ---------------- Flash attention: R15 base + PV via 16x16x32 f16 -------------
// Barrier-free, QBLK=128, wave=(qh,kh), grid 512, depth-2 ping-pong.
// PV now 16 MFMA/tile (x32 f16) instead of 32 (x16): key-permuted K packing
// makes QK output land directly in x32 A-frag order (keys quad*8+{0..7}).
__device__ __forceinline__ void load_tile(const bf16* Kt, const f16* Vt, int kh, int lane,
                                          bf16x8 kf[2][2], f16x8 vf[4]) {
#pragma unroll
    for (int ks = 0; ks < 2; ks++)
#pragma unroll
        for (int n = 0; n < 2; n++)
            kf[ks][n] = *(const bf16x8*)&Kt[((kh * 2 + n) * 2 + ks) * 512 + lane * 8];
#pragma unroll
    for (int jd = 0; jd < 4; jd++)
        vf[jd] = *(const f16x8*)&Vt[jd * 512 + lane * 8];
}

__device__ __forceinline__ void compute_tile(const bf16x8 kf[2][2], const f16x8 vf[4],
                                             const bf16x8 qf[4][2],
                                             f32x4 oacc[4][4], float lsum[4]) {
    f32x4 sacc[4][2];
#pragma unroll
    for (int t = 0; t < 4; t++)
#pragma unroll
        for (int n = 0; n < 2; n++) sacc[t][n] = f32x4{-8.f, -8.f, -8.f, -8.f};
    __builtin_amdgcn_s_setprio(1);
#pragma unroll
    for (int ks = 0; ks < 2; ks++)
#pragma unroll
        for (int t = 0; t < 4; t++)
#pragma unroll
            for (int n = 0; n < 2; n++)
                sacc[t][n] = MFMA16(kf[ks][n], qf[t][ks], sacc[t][n]);
    __builtin_amdgcn_s_setprio(0);

    // p = exp2(s-8); pack to f16x8 A-frags (elem e = n*4+r -> key quad*8+e)
    f16x8 pa[4];
#pragma unroll
    for (int t = 0; t < 4; t++) {
        float p0 = __builtin_amdgcn_exp2f(sacc[t][0][0]);
        float p1 = __builtin_amdgcn_exp2f(sacc[t][0][1]);
        float p2 = __builtin_amdgcn_exp2f(sacc[t][0][2]);
        float p3 = __builtin_amdgcn_exp2f(sacc[t][0][3]);
        float p4 = __builtin_amdgcn_exp2f(sacc[t][1][0]);
        float p5 = __builtin_amdgcn_exp2f(sacc[t][1][1]);
        float p6 = __builtin_amdgcn_exp2f(sacc[t][1][2]);
        float p7 = __builtin_amdgcn_exp2f(sacc[t][1][3]);
        lsum[t] += ((p0 + p1) + (p2 + p3)) + ((p4 + p5) + (p6 + p7));
        u32 a0 = __builtin_bit_cast(u32, __builtin_amdgcn_cvt_pkrtz(p0, p1));
        u32 a1 = __builtin_bit_cast(u32, __builtin_amdgcn_cvt_pkrtz(p2, p3));
        u32 a2 = __builtin_bit_cast(u32, __builtin_amdgcn_cvt_pkrtz(p4, p5));
        u32 a3 = __builtin_bit_cast(u32, __builtin_amdgcn_cvt_pkrtz(p6, p7));
        u32x4 packed = {a0, a1, a2, a3};
        pa[t] = __builtin_bit_cast(f16x8, packed);
    }

    __builtin_amdgcn_s_setprio(1);
#pragma unroll
    for (int jd = 0; jd < 4; jd++)
#pragma unroll
        for (int t = 0; t < 4; t++)
            oacc[t][jd] = MFMAF16X32(pa[t], vf[jd], oacc[t][jd]);
    __builtin_amdgcn_s_setprio(0);
}

__global__ __launch_bounds__(256, 2) void attn_kernel(
    const bf16* __restrict__ qp, const bf16* __restrict__ kp,
    const f16* __restrict__ vp, bf16* __restrict__ o)
{
    __shared__ __align__(16) char smem[35328];   // epilogue Pt (34816) + lsumL (512)

    const int tid = threadIdx.x, wave = tid >> 6, lane = tid & 63;
    const int lrow = lane & 15, quad = lane >> 4;
    const int qh = wave & 1, kh = wave >> 1;
    const int bh = blockIdx.x & 31, qt = blockIdx.x >> 5;   // bh fastest -> XCD-pinned
    const bf16* Qb = qp + ((long)bh * 32 + qt * 2 + qh) * 4096;
    const bf16* Kb = kp + (long)bh * 32 * 4096;
    const f16*  Vb = vp + (long)bh * 32 * 4096 + kh * 2048;

    // Q fragments (64 rows) once
    bf16x8 qf[4][2];
#pragma unroll
    for (int t = 0; t < 4; t++)
#pragma unroll
        for (int ks = 0; ks < 2; ks++)
            qf[t][ks] = *(const bf16x8*)&Qb[(t * 2 + ks) * 512 + lane * 8];

    f32x4 oacc[4][4] = {};
    float lsum[4] = {0.f, 0.f, 0.f, 0.f};

    bf16x8 kA[2][2], kB[2][2];
    f16x8  vA[4], vB[4];
    load_tile(Kb, Vb, kh, lane, kA, vA);                 // tile 0

    for (int kv = 0; kv < 32; kv += 2) {
        load_tile(Kb + (kv + 1) * 4096, Vb + (long)(kv + 1) * 4096, kh, lane, kB, vB);
        compute_tile(kA, vA, qf, oacc, lsum);
        if (kv < 30)
            load_tile(Kb + (kv + 2) * 4096, Vb + (long)(kv + 2) * 4096, kh, lane, kA, vA);
        compute_tile(kB, vB, qf, oacc, lsum);
    }

    // ---- in-wave l reduce (across quads) ----
#pragma unroll
    for (int t = 0; t < 4; t++) {
        lsum[t] += __shfl_xor(lsum[t], 16, 64);
        lsum[t] += __shfl_xor(lsum[t], 32, 64);
    }

    // ---- epilogue: combine kh halves ----
    float* Pt  = (float*)smem;                // [2][64*68]
    float* lsL = (float*)(smem + 34816);      // [2][64]
    float* Pr  = Pt + qh * (64 * 68);
    if (kh == 1) {
#pragma unroll
        for (int t = 0; t < 4; t++)
#pragma unroll
            for (int jd = 0; jd < 4; jd++)
                *(f32x4*)&Pr[lane * 68 + (t * 4 + jd) * 4] = oacc[t][jd];
        if (quad == 0)
#pragma unroll
            for (int t = 0; t < 4; t++) lsL[qh * 64 + t * 16 + lrow] = lsum[t];
    }
    __syncthreads();
    if (kh == 0) {
#pragma unroll
        for (int t = 0; t < 4; t++)
#pragma unroll
            for (int jd = 0; jd < 4; jd++)
                oacc[t][jd] += *(const f32x4*)&Pr[lane * 68 + (t * 4 + jd) * 4];
#pragma unroll
        for (int t = 0; t < 4; t++) lsum[t] += lsL[qh * 64 + t * 16 + lrow];

        // transpose-store via Pr reused as bf16 [64][72]
        bf16* Tw = (bf16*)Pr;
        const int b = bh >> 4, h = bh & 15;
#pragma unroll
        for (int t = 0; t < 4; t++) {
            float linv = 1.0f / lsum[t];
#pragma unroll
            for (int r = 0; r < 4; r++) {
                float lr = __shfl(linv, quad * 4 + r, 64);
#pragma unroll
                for (int jd = 0; jd < 4; jd++)
                    Tw[(t * 16 + quad * 4 + r) * 72 + jd * 16 + lrow] = (bf16)(oacc[t][jd][r] * lr);
            }
        }
        const int rr = lane >> 3, cc = (lane & 7) * 8;   // in-wave dep only
#pragma unroll
        for (int p = 0; p < 8; p++) {
            bf16x8 val = *(const bf16x8*)&Tw[(rr + p * 8) * 72 + cc];
            int n = qt * 128 + qh * 64 + rr + p * 8;
            *(bf16x8*)&o[((long)(b * 2048 + n)) * 1024 + h * 64 + cc] = val;
        }
    }
}

// ---------------- GEMM2: 128x64, dbuf, f32x4 stores -----------------------------
__global__ __launch_bounds__(256, 2) void gemm_proj(
    const bf16* __restrict__ A, const bf16* __restrict__ Bm, float* __restrict__ out)
{
    __shared__ bf16 As[2][128 * 32];
    __shared__ bf16 Bs[2][64 * 32];
    const int tid = threadIdx.x;
    const int wave = tid >> 6, lane = tid & 63;
    const int lrow = lane & 15, quad = lane >> 4;
    const int wm = (wave >> 1) * 64, wn = (wave & 1) * 32;
    const int srow = tid >> 2;
    const int scol = ((tid & 3) ^ (srow & 3)) * 8;
    const int fsw = (quad ^ (lrow & 3)) * 8;

    const bf16* Ap = A + (long)(blockIdx.x * 128 + srow) * 1024 + scol;
    const bf16* Bp = Bm + (long)(blockIdx.y * 64 + srow) * 1024 + scol;

    f32x4 acc[4][2] = {};

    gll(Ap, &As[0][tid * 8]);  gll(Ap + 64 * 1024, &As[0][2048 + tid * 8]);
    gll(Bp, &Bs[0][tid * 8]);

    for (int i = 0; i < 32; i++) {
        const int cur = i & 1;
        __syncthreads();
        if (i < 31) {
            const int k0 = (i + 1) * 32;
            gll(Ap + k0, &As[cur ^ 1][tid * 8]);
            gll(Ap + 64 * 1024 + k0, &As[cur ^ 1][2048 + tid * 8]);
            gll(Bp + k0, &Bs[cur ^ 1][tid * 8]);
        }
        bf16x8 af[4], bfr[2];
#pragma unroll
        for (int ii = 0; ii < 4; ii++) af[ii] = *(const bf16x8*)&As[cur][(wm + ii * 16 + lrow) * 32 + fsw];
#pragma unroll
        for (int j = 0; j < 2; j++) bfr[j] = *(const bf16x8*)&Bs[cur][(wn + j * 16 + lrow) * 32 + fsw];
#pragma unroll
        for (int ii = 0; ii < 4; ii++)
#pragma unroll
            for (int j = 0; j < 2; j++)
                acc[ii][j] = MFMA16(bfr[j], af[ii], acc[ii][j]);   // transposed: r along o
    }

    const int gm0 = blockIdx.x * 128 + wm;
    const int go0 = blockIdx.y * 64 + wn;
#pragma unroll
    for (int i = 0; i < 4; i++) {
        int gm = gm0 + i * 16 + lrow;
#pragma unroll
        for (int j = 0; j < 2; j++) {
            int ob = go0 + j * 16 + quad * 4;
            *(f32x4*)&out[(long)gm * 1024 + ob] = acc[i][j];
        }
    }
}

// ---------------- launch ----------------
extern "C" void kernel_launch(void* const* d_in, const int* in_sizes, int n_in,
                              void* d_out, int out_size, void* d_ws, size_t ws_size,
                              hipStream_t stream) {
    const float* x      = (const float*)d_in[0];   // [2,2048,1024]
    const float* w_qkv  = (const float*)d_in[1];   // [3072,1024]
    const float* w_proj = (const float*)d_in[2];   // [1024,1024]
    float* out = (float*)d_out;                    // [2,2048,1024]

    bf16* ws = (bf16*)d_ws;
    bf16* xb     = ws;                       // 4096*1024
    bf16* wqkvb  = xb + 4096 * 1024;         // 3072*1024
    bf16* wprojb = wqkvb + 3072 * 1024;      // 1024*1024
    bf16* qb     = wprojb + 1024 * 1024;     // packed [32][32][8][512] bf16
    bf16* kb     = qb + 2 * 16 * 2048 * 64;  // packed (key-permuted), same size
    f16*  vb     = (f16*)(kb + 2 * 16 * 2048 * 64);  // packed [32][32][2][4][512] f16
    bf16* ob     = (bf16*)(vb + 2 * 16 * 2048 * 64); // 4096*1024 bf16

    cvt_all<<<8192, 256, 0, stream>>>(x, w_qkv, w_proj, xb, wqkvb, wprojb);
    gemm_qkv<<<dim3(32, 24), 256, 0, stream>>>(xb, wqkvb, qb, kb, vb);
    attn_kernel<<<512, 256, 0, stream>>>(qb, kb, vb, ob);
    gemm_proj<<<dim3(32, 16), 256, 0, stream>>>(ob, wprojb, out);
}